// Round 5
// baseline (93.100 us; speedup 1.0000x reference)
//
#include <hip/hip_runtime.h>
#include <hip/hip_bf16.h>
#include <math.h>

#define HW 16384          // 128*128
#define IMG 128
#define C_IN 128
#define C_OUT 64
#define NB 8
#define NE 4

static __device__ __forceinline__ unsigned short f2bf(float f) {
  union { float f; unsigned int u; } v; v.f = f;
  unsigned int r = v.u + 0x7FFF + ((v.u >> 16) & 1);   // RNE
  return (unsigned short)(r >> 16);
}
static __device__ __forceinline__ float bf2f(unsigned short h) {
  union { unsigned int u; float f; } v; v.u = ((unsigned int)h) << 16;
  return v.f;
}

// ---- K1: pre-fuse 1x1 conv + fused partial pooling (bf16 x1 out) ----
// 512 thr = 8 waves; wave g -> outputs [8g,8g+8); thread: 8 px.
// 4-deep x prefetch ring + 1-deep weight double buffer.
__global__ __launch_bounds__(512) void prefuse_kernel(
    const float* __restrict__ x, const float* __restrict__ pre_w,
    const float* __restrict__ pre_b, unsigned short* __restrict__ x1,
    float* __restrict__ pmax, float* __restrict__ psum) {
  __shared__ float wt[C_IN * C_OUT];  // wt[c*64 + o] = pre_w[o*128 + c]
  int tid = threadIdx.x;
  for (int i = tid; i < C_IN * C_OUT; i += 512) {
    int cc = i >> 6, oo = i & 63;
    wt[i] = pre_w[oo * C_IN + cc];
  }
  int g = tid >> 6, lane = tid & 63;
  int blk = blockIdx.x;               // 256 blocks; 32 per batch
  int b = blk >> 5;
  int part = blk & 31;
  int hw0 = part * 512 + lane * 4;    // first float4; second at +256
  const float* xp = x + (size_t)b * C_IN * HW + hw0;
  int ob = g * 8;

  float4 acc[16];                     // 8 outputs x 8 px
#pragma unroll
  for (int o = 0; o < 8; ++o) {
    float bv = pre_b[ob + o];
    acc[2 * o]     = make_float4(bv, bv, bv, bv);
    acc[2 * o + 1] = make_float4(bv, bv, bv, bv);
  }
  __syncthreads();

  float4 xf[4][2];
#pragma unroll
  for (int d = 0; d < 4; ++d) {
    xf[d][0] = *(const float4*)(xp + (size_t)d * HW);
    xf[d][1] = *(const float4*)(xp + (size_t)d * HW + 256);
  }
  float4 wb[2][2];
  wb[0][0] = *(const float4*)(wt + ob);
  wb[0][1] = *(const float4*)(wt + ob + 4);

#pragma unroll 4
  for (int c = 0; c < C_IN; ++c) {
    float4 a0 = xf[c & 3][0], a1 = xf[c & 3][1];
    float4 w0 = wb[c & 1][0], w1 = wb[c & 1][1];
    if (c + 1 < C_IN) {
      wb[(c + 1) & 1][0] = *(const float4*)(wt + (c + 1) * C_OUT + ob);
      wb[(c + 1) & 1][1] = *(const float4*)(wt + (c + 1) * C_OUT + ob + 4);
    }
    if (c + 4 < C_IN) {
      xf[c & 3][0] = *(const float4*)(xp + (size_t)(c + 4) * HW);
      xf[c & 3][1] = *(const float4*)(xp + (size_t)(c + 4) * HW + 256);
    }
    const float* wp = (const float*)&w0;
#pragma unroll
    for (int o = 0; o < 4; ++o) {
      float wv = wp[o];
      acc[2*o].x   = fmaf(a0.x, wv, acc[2*o].x);
      acc[2*o].y   = fmaf(a0.y, wv, acc[2*o].y);
      acc[2*o].z   = fmaf(a0.z, wv, acc[2*o].z);
      acc[2*o].w   = fmaf(a0.w, wv, acc[2*o].w);
      acc[2*o+1].x = fmaf(a1.x, wv, acc[2*o+1].x);
      acc[2*o+1].y = fmaf(a1.y, wv, acc[2*o+1].y);
      acc[2*o+1].z = fmaf(a1.z, wv, acc[2*o+1].z);
      acc[2*o+1].w = fmaf(a1.w, wv, acc[2*o+1].w);
    }
    const float* wq = (const float*)&w1;
#pragma unroll
    for (int o = 0; o < 4; ++o) {
      float wv = wq[o];
      int oo = o + 4;
      acc[2*oo].x   = fmaf(a0.x, wv, acc[2*oo].x);
      acc[2*oo].y   = fmaf(a0.y, wv, acc[2*oo].y);
      acc[2*oo].z   = fmaf(a0.z, wv, acc[2*oo].z);
      acc[2*oo].w   = fmaf(a0.w, wv, acc[2*oo].w);
      acc[2*oo+1].x = fmaf(a1.x, wv, acc[2*oo+1].x);
      acc[2*oo+1].y = fmaf(a1.y, wv, acc[2*oo+1].y);
      acc[2*oo+1].z = fmaf(a1.z, wv, acc[2*oo+1].z);
      acc[2*oo+1].w = fmaf(a1.w, wv, acc[2*oo+1].w);
    }
  }

#pragma unroll
  for (int o = 0; o < 8; ++o) {
    float4 a0 = acc[2 * o], a1 = acc[2 * o + 1];
    unsigned short* op = x1 + ((size_t)b * C_OUT + ob + o) * HW + hw0;
    uint2 p0, p1;
    p0.x = ((unsigned)f2bf(a0.y) << 16) | f2bf(a0.x);
    p0.y = ((unsigned)f2bf(a0.w) << 16) | f2bf(a0.z);
    p1.x = ((unsigned)f2bf(a1.y) << 16) | f2bf(a1.x);
    p1.y = ((unsigned)f2bf(a1.w) << 16) | f2bf(a1.z);
    *(uint2*)op = p0;
    *(uint2*)(op + 256) = p1;
    // pooling partials from exact fp32 accumulators
    float m = fmaxf(fmaxf(fmaxf(a0.x, a0.y), fmaxf(a0.z, a0.w)),
                    fmaxf(fmaxf(a1.x, a1.y), fmaxf(a1.z, a1.w)));
    float s = ((a0.x + a0.y) + (a0.z + a0.w)) + ((a1.x + a1.y) + (a1.z + a1.w));
#pragma unroll
    for (int d = 32; d >= 1; d >>= 1) {
      m = fmaxf(m, __shfl_xor(m, d));
      s += __shfl_xor(s, d);
    }
    if (lane == 0) {
      int bo = b * C_OUT + ob + o;
      pmax[bo * 32 + part] = m;
      psum[bo * 32 + part] = s;
    }
  }
}

// ---- K2: finish pooling + gate network -> cof[B][E] ----
__global__ __launch_bounds__(512) void pool_gate_kernel(
    const float* __restrict__ pmax, const float* __restrict__ psum,
    const float* __restrict__ gw0, const float* __restrict__ gb0,
    const float* __restrict__ gw1, const float* __restrict__ gb1,
    float* __restrict__ cof) {
  __shared__ float pooled[NB * C_OUT];
  int bo = threadIdx.x;  // 0..511
  float m = -INFINITY, s = 0.f;
  for (int k = 0; k < 32; ++k) {
    m = fmaxf(m, pmax[bo * 32 + k]);
    s += psum[bo * 32 + k];
  }
  pooled[bo] = m + s * (1.0f / HW);
  __syncthreads();

  int b = threadIdx.x;
  if (b >= NB) return;
  float logits[NE], noise[NE];
#pragma unroll
  for (int e = 0; e < NE; ++e) {
    float d0 = gb0[e], d1 = gb1[e];
    for (int k = 0; k < C_OUT; ++k) {
      float pv = pooled[b * C_OUT + k];
      d0 = fmaf(pv, gw0[e * C_OUT + k], d0);
      d1 = fmaf(pv, gw1[e * C_OUT + k], d1);
    }
    logits[e] = d1 > 0.f ? d1 : 0.2f * d1;
    noise[e] = log1pf(expf(d0));
  }
  float mn = 0.25f * (noise[0] + noise[1] + noise[2] + noise[3]);
  float var = 0.f;
#pragma unroll
  for (int e = 0; e < NE; ++e) { float d = noise[e] - mn; var += d * d; }
  float sd = sqrtf(var * (1.0f / 3.0f));
  float scores[NE];
#pragma unroll
  for (int e = 0; e < NE; ++e) scores[e] = logits[e] + (noise[e] - mn) / sd;
  int i0 = 0;
#pragma unroll
  for (int e = 1; e < NE; ++e) if (scores[e] > scores[i0]) i0 = e;
  int i1 = -1;
#pragma unroll
  for (int e = 0; e < NE; ++e)
    if (e != i0 && (i1 < 0 || scores[e] > scores[i1])) i1 = e;
  float mm = fmaxf(logits[i0], logits[i1]);
  float e0 = expf(logits[i0] - mm), e1 = expf(logits[i1] - mm);
  float inv = 1.0f / (e0 + e1);
#pragma unroll
  for (int e = 0; e < NE; ++e) cof[b * NE + e] = 0.f;
  cof[b * NE + i0] = e0 * inv;
  cof[b * NE + i1] = e1 * inv;
}

// ---- K3: fused experts (bf16 x1 input), vectorized LDS, cof==0 skip ----
__global__ __launch_bounds__(256) void expert_kernel(
    const unsigned short* __restrict__ x1, const float* __restrict__ ew1,
    const float* __restrict__ eb1, const float* __restrict__ ew2,
    const float* __restrict__ eb2, const float* __restrict__ cof,
    float* __restrict__ out) {
  __shared__ float xs[36 * 36 + 8];   // stride 36
  __shared__ float hs[34 * 36 + 8];   // stride 36, cols 0..33 valid
  int tid = threadIdx.x;
  int blk = blockIdx.x;
  int tile = blk & 15;
  int c = (blk >> 4) & 63;
  int b = blk >> 10;
  int ty0 = (tile >> 2) * 32, tx0 = (tile & 3) * 32;
  const unsigned short* xp = x1 + ((size_t)b * C_OUT + c) * HW;

  // stage 36x36 x-tile (halo 2), zero outside image, bf16 -> fp32
  for (int i = tid; i < 36 * 36; i += 256) {
    int iy = i / 36, ix = i - iy * 36;
    int gy = ty0 - 2 + iy, gx = tx0 - 2 + ix;
    float v = 0.f;
    if ((unsigned)gy < 128u && (unsigned)gx < 128u) v = bf2f(xp[gy * IMG + gx]);
    xs[i] = v;
  }

  int row2 = tid >> 3;          // 0..31
  int oc0 = (tid & 7) * 4;      // 0,4,...,28
  float acc[4] = {0.f, 0.f, 0.f, 0.f};

  for (int e = 0; e < NE; ++e) {
    float cf = cof[b * NE + e];
    if (cf == 0.f) continue;    // uniform per block: exactly 2 active experts
    float w1[9], w2[9];
#pragma unroll
    for (int k = 0; k < 9; ++k) {
      w1[k] = ew1[((size_t)e * C_OUT + c) * 9 + k];
      w2[k] = ew2[((size_t)e * C_OUT + c) * 9 + k];
    }
    float b1 = eb1[e * C_OUT + c], b2 = eb2[e * C_OUT + c];

    __syncthreads();   // xs ready / hs free

    // h = gelu(conv1(x)) over 34 rows x 9 groups of 4 cols
    for (int t = tid; t < 34 * 9; t += 256) {
      int hr = t / 9;
      int g4 = t - hr * 9;
      int hc0 = g4 * 4;
      const float* xr = xs + hr * 36 + hc0;
      float xv[3][6];
#pragma unroll
      for (int dy = 0; dy < 3; ++dy) {
        float4 a = *(const float4*)(xr + dy * 36);
        float2 bb = *(const float2*)(xr + dy * 36 + 4);
        xv[dy][0] = a.x; xv[dy][1] = a.y; xv[dy][2] = a.z; xv[dy][3] = a.w;
        xv[dy][4] = bb.x; xv[dy][5] = bb.y;
      }
      int gy = ty0 - 1 + hr;
      int gx0 = tx0 - 1 + hc0;
      float4 hv;
      float* hvp = (float*)&hv;
#pragma unroll
      for (int j = 0; j < 4; ++j) {
        float s = b1;
#pragma unroll
        for (int dy = 0; dy < 3; ++dy)
#pragma unroll
          for (int dx = 0; dx < 3; ++dx)
            s = fmaf(xv[dy][j + dx], w1[dy * 3 + dx], s);
        float u = s * s;
        float tp = 1.f - u * (0.16666667f - u * (0.025f - u * 0.0029761905f));
        float h = s * fmaf(0.3989422804f * s, tp, 0.5f);
        bool ok = ((unsigned)gy < 128u) && ((unsigned)(gx0 + j) < 128u);
        hvp[j] = ok ? h : 0.f;
      }
      *(float4*)(hs + hr * 36 + hc0) = hv;
    }
    __syncthreads();   // hs ready

    const float* hp = hs + row2 * 36 + oc0;
    float s0 = b2, s1 = b2, s2 = b2, s3 = b2;
#pragma unroll
    for (int dy = 0; dy < 3; ++dy) {
      float4 a = *(const float4*)(hp + dy * 36);
      float2 bb = *(const float2*)(hp + dy * 36 + 4);
      float h0 = a.x, h1 = a.y, h2 = a.z, h3 = a.w, h4 = bb.x, h5 = bb.y;
      float wA = w2[dy * 3], wB = w2[dy * 3 + 1], wC = w2[dy * 3 + 2];
      s0 = fmaf(h0, wA, fmaf(h1, wB, fmaf(h2, wC, s0)));
      s1 = fmaf(h1, wA, fmaf(h2, wB, fmaf(h3, wC, s1)));
      s2 = fmaf(h2, wA, fmaf(h3, wB, fmaf(h4, wC, s2)));
      s3 = fmaf(h3, wA, fmaf(h4, wB, fmaf(h5, wC, s3)));
    }
    acc[0] = fmaf(cf, s0, acc[0]);
    acc[1] = fmaf(cf, s1, acc[1]);
    acc[2] = fmaf(cf, s2, acc[2]);
    acc[3] = fmaf(cf, s3, acc[3]);
  }

  float4 o4 = make_float4(acc[0], acc[1], acc[2], acc[3]);
  *(float4*)(out + ((size_t)b * C_OUT + c) * HW + (ty0 + row2) * IMG + tx0 + oc0) = o4;
}

extern "C" void kernel_launch(void* const* d_in, const int* in_sizes, int n_in,
                              void* d_out, int out_size, void* d_ws, size_t ws_size,
                              hipStream_t stream) {
  const float* x     = (const float*)d_in[0];
  const float* pre_w = (const float*)d_in[1];
  const float* pre_b = (const float*)d_in[2];
  const float* gw0   = (const float*)d_in[3];
  const float* gb0   = (const float*)d_in[4];
  const float* gw1   = (const float*)d_in[5];
  const float* gb1   = (const float*)d_in[6];
  const float* ew1   = (const float*)d_in[7];
  const float* eb1   = (const float*)d_in[8];
  const float* ew2   = (const float*)d_in[9];
  const float* eb2   = (const float*)d_in[10];
  float* out = (float*)d_out;

  char* ws = (char*)d_ws;
  unsigned short* x1 = (unsigned short*)ws;            // bf16, 16.78 MiB
  float* pmax = (float*)(ws + 33554432);               // 512*32 fp32
  float* psum = (float*)(ws + 33554432 + 65536);
  float* cof  = (float*)(ws + 33554432 + 131072);

  prefuse_kernel<<<256, 512, 0, stream>>>(x, pre_w, pre_b, x1, pmax, psum);
  pool_gate_kernel<<<1, 512, 0, stream>>>(pmax, psum, gw0, gb0, gw1, gb1, cof);
  expert_kernel<<<8192, 256, 0, stream>>>(x1, ew1, eb1, ew2, eb2, cof, out);
}